// Round 11
// baseline (436.831 us; speedup 1.0000x reference)
//
#include <hip/hip_runtime.h>
#include <hip/hip_bf16.h>

#define N_NODES 50000
#define N_EDGES 800000

typedef __bf16 bf16x8 __attribute__((ext_vector_type(8)));
typedef float f32x4 __attribute__((ext_vector_type(4)));

__device__ __forceinline__ float loadF(const void* p, size_t i, bool isbf) {
    return isbf ? __bfloat162float(((const __hip_bfloat16*)p)[i]) : ((const float*)p)[i];
}
__device__ __forceinline__ float bfbits2f(unsigned short u) {
    return __uint_as_float(((unsigned)u) << 16);
}
__device__ __forceinline__ unsigned short f2bfbits(float f) {
    __hip_bfloat16 h = __float2bfloat16(f);
    return *(unsigned short*)&h;
}

// ---------- convert (with built-in per-block dtype detect) ----------
// x -> bf16 row-major; W1/W2/Wo -> fragment-major Wf:
// unit u = (s*Npad + n)*4 + quad holds 8 shorts: W[s*32+quad*8+j][n]
__global__ void cvt_all_k(const void* __restrict__ x, const void* __restrict__ W1,
                          const void* __restrict__ W2, const void* __restrict__ Wo,
                          unsigned short* __restrict__ Xb, unsigned short* __restrict__ W1f,
                          unsigned short* __restrict__ W2f, unsigned short* __restrict__ Wof,
                          int* __restrict__ flag) {
    __shared__ int s_flag;
    int t = threadIdx.x;
    if (t < 64) {
        const unsigned short* xw = (const unsigned short*)x;
        int cnt = 0;
        for (int i = t; i < 512; i += 64) {
            unsigned e = (xw[2 * i] >> 7) & 0xFFu;
            if (e >= 117u && e <= 134u) cnt++;
        }
        for (int off = 32; off; off >>= 1) cnt += __shfl_down(cnt, off, 64);
        if (t == 0) s_flag = (cnt >= 256) ? 1 : 0;
    }
    __syncthreads();
    bool bf = (s_flag != 0);
    int i = blockIdx.x * blockDim.x + t;
    if (i == 0) *flag = s_flag ? 1 : 0;
    if (i < 800000) {
        if (bf) {
            ((uint4*)Xb)[i] = ((const uint4*)x)[i];
        } else {
            const float* f = (const float*)x + (size_t)i * 8;
            unsigned short r[8];
            for (int j = 0; j < 8; ++j) r[j] = f2bfbits(f[j]);
            *(uint4*)(Xb + (size_t)i * 8) = *(uint4*)r;
        }
        return;
    }
    int u = i - 800000;
    const void* W; unsigned short* dst; int Nf, Npad, s, rem;
    if (u < 4096)        { W = W1; dst = W1f; Nf = 256; Npad = 256; s = u / 1024; rem = u % 1024; }
    else if (u < 12288)  { u -= 4096;  W = W2; dst = W2f; Nf = 256; Npad = 256; s = u / 1024; rem = u % 1024; }
    else if (u < 14336)  { u -= 12288; W = Wo; dst = Wof; Nf = 40;  Npad = 64;  s = u / 256;  rem = u % 256; }
    else return;
    int n = rem >> 2, quad = rem & 3;
    unsigned short r[8];
    for (int j = 0; j < 8; ++j) {
        int k = s * 32 + quad * 8 + j;
        r[j] = (n < Nf) ? f2bfbits(loadF(W, (size_t)k * Nf + n, bf)) : (unsigned short)0;
    }
    int uo = (s * Npad + n) * 4 + quad;
    *(uint4*)(dst + (size_t)uo * 8) = *(uint4*)r;
}

// ---------- CSR build ----------
__global__ void hist_k(const int* __restrict__ dst, int* __restrict__ cnt, int E) {
    int e = blockIdx.x * blockDim.x + threadIdx.x;
    if (e < E) atomicAdd(&cnt[dst[e]], 1);
}

__global__ void scan1_k(const int* __restrict__ deg, int* __restrict__ rowptr,
                        int* __restrict__ bsum, int N) {
    __shared__ int s[256];
    int t = threadIdx.x, g = blockIdx.x * 256 + t;
    int v = (g < N) ? deg[g] : 0;
    s[t] = v; __syncthreads();
    for (int off = 1; off < 256; off <<= 1) {
        int x = (t >= off) ? s[t - off] : 0;
        __syncthreads();
        s[t] += x;
        __syncthreads();
    }
    if (g < N) rowptr[g] = s[t] - v;
    if (t == 255) bsum[blockIdx.x] = s[255];
}

__global__ void scan23_k(int* __restrict__ rowptr, const int* __restrict__ bsum, int N, int E) {
    __shared__ int ws[4];
    __shared__ int s_off;
    int bid = blockIdx.x, t = threadIdx.x;
    int wave = t >> 6, lane = t & 63;
    int v = (t < bid) ? bsum[t] : 0;
    for (int off = 32; off; off >>= 1) v += __shfl_down(v, off, 64);
    if (lane == 0) ws[wave] = v;
    __syncthreads();
    if (t == 0) s_off = ws[0] + ws[1] + ws[2] + ws[3];
    __syncthreads();
    int g = bid * 256 + t;
    if (g < N) rowptr[g] += s_off;
    if (g == 0) rowptr[N] = E;
}

__global__ void scatter_k(const int* __restrict__ src, const int* __restrict__ dst,
                          const int* __restrict__ rowptr, int* __restrict__ cursor,
                          int* __restrict__ ecol, int E) {
    int e = blockIdx.x * blockDim.x + threadIdx.x;
    if (e >= E) return;
    int d = dst[e];
    int r = atomicSub(&cursor[d], 1);
    ecol[rowptr[d] + r - 1] = src[e];
}

// ---------- LDS-free MFMA GEMM + fused attention coefficients ----------
template <int K_, int AMODE>
__global__ __launch_bounds__(256)
void gemm_attn_k(const unsigned short* __restrict__ A, const unsigned short* __restrict__ Wf,
                 __hip_bfloat16* __restrict__ C, const void* __restrict__ al,
                 const void* __restrict__ ar, const int* __restrict__ flag,
                 float* __restrict__ el, float* __restrict__ er, int M, int Nfull, int Npad) {
    int t = threadIdx.x;
    int row0 = blockIdx.x * 128, col0 = blockIdx.y * 64;
    int wave = t >> 6, lane = t & 63;
    int wr = (wave >> 1) * 64, wc = (wave & 1) * 32;
    int m16 = lane & 15, quad = lane >> 4;

    const unsigned short* arow[4];
    for (int mt = 0; mt < 4; ++mt) {
        int gr = row0 + wr + mt * 16 + m16;
        int grc = (gr < M) ? gr : (M - 1);
        arow[mt] = A + (size_t)grc * K_ + quad * 8;
    }
    const unsigned short* bbase[2];
    for (int nt = 0; nt < 2; ++nt) {
        int gc = col0 + wc + nt * 16 + m16;
        bbase[nt] = Wf + ((size_t)(gc * 4 + quad) << 3);
    }

    f32x4 acc[4][2] = {};
#pragma unroll
    for (int s = 0; s < K_ / 32; ++s) {
        bf16x8 a[4], b[2];
        for (int mt = 0; mt < 4; ++mt)
            a[mt] = *(const bf16x8*)(arow[mt] + s * 32);
        for (int nt = 0; nt < 2; ++nt)
            b[nt] = *(const bf16x8*)(bbase[nt] + (size_t)s * Npad * 32);
        for (int mt = 0; mt < 4; ++mt)
            for (int nt = 0; nt < 2; ++nt)
                acc[mt][nt] = __builtin_amdgcn_mfma_f32_16x16x32_bf16(
                    a[mt], b[nt], acc[mt][nt], 0, 0, 0);
    }

    int cld = (AMODE == 0) ? Nfull : Npad;
    for (int mt = 0; mt < 4; ++mt)
        for (int nt = 0; nt < 2; ++nt)
            for (int r = 0; r < 4; ++r) {
                int gr = row0 + wr + mt * 16 + quad * 4 + r;
                int gc = col0 + wc + nt * 16 + m16;
                if (gr < M && gc < cld)
                    C[(size_t)gr * cld + gc] = __float2bfloat16(acc[mt][nt][r]);
            }

    bool bf = (*flag != 0);
    float alc[2], arc[2];
    for (int nt = 0; nt < 2; ++nt) {
        int gc = col0 + wc + nt * 16 + m16;
        bool ok = gc < Nfull;
        alc[nt] = ok ? loadF(al, gc, bf) : 0.f;
        arc[nt] = ok ? loadF(ar, gc, bf) : 0.f;
    }
    for (int mt = 0; mt < 4; ++mt)
        for (int r = 0; r < 4; ++r) {
            float pl = acc[mt][0][r] * alc[0] + acc[mt][1][r] * alc[1];
            float pr = acc[mt][0][r] * arc[0] + acc[mt][1][r] * arc[1];
            for (int off = 1; off < 16; off <<= 1) {
                pl += __shfl_xor(pl, off, 64);
                pr += __shfl_xor(pr, off, 64);
            }
            if (m16 == 0) {
                int gr = row0 + wr + mt * 16 + quad * 4 + r;
                if (gr < M) {
                    if (AMODE == 0) {
                        int hd = col0 / 32 + (wave & 1);
                        el[gr * 8 + hd] = pl;
                        er[gr * 8 + hd] = pr;
                    } else {
                        atomicAdd(&el[gr], pl);
                        atomicAdd(&er[gr], pr);
                    }
                }
            }
        }
}

// ---------- single-pass half-wave aggregation (H=8, F=32) ----------
// 8-edge chunks with next-chunk ecol prefetch: ~1 memory round-trip per chunk.
__global__ __launch_bounds__(256)
void aggr1_k(const int* __restrict__ rowptr, const int* __restrict__ ecol,
             const float* __restrict__ el, const float* __restrict__ er,
             const __hip_bfloat16* __restrict__ Hp, __hip_bfloat16* __restrict__ out, int N) {
    int t = threadIdx.x;
    int hw = t >> 5, l = t & 31;
    int n = blockIdx.x * 8 + hw;
    if (n >= N) return;
    int beg = rowptr[n], deg = rowptr[n + 1] - beg;

    int hh = l >> 2;
    float er_hh = er[n * 8 + hh];
    float ss = 0.f;
    float acc[8] = {0.f, 0.f, 0.f, 0.f, 0.f, 0.f, 0.f, 0.f};
    const unsigned short* hp = (const unsigned short*)Hp;

    int nfull = deg & ~7;
    int s_cur[8];
#pragma unroll
    for (int k = 0; k < 8; ++k) s_cur[k] = (k < deg) ? ecol[beg + k] : 0;

    for (int base = 0; base < nfull; base += 8) {
        // prefetch next chunk's edge ids
        int s_nxt[8];
        int nb = base + 8;
        bool more = (nb < nfull);
#pragma unroll
        for (int k = 0; k < 8; ++k) s_nxt[k] = more ? ecol[beg + nb + k] : 0;

        // issue all 8 Hp row gathers
        uint4 r[8];
#pragma unroll
        for (int k = 0; k < 8; ++k)
            r[k] = *(const uint4*)(hp + (size_t)s_cur[k] * 256 + l * 8);

        // logits for the 8 edges
        float ex[8];
#pragma unroll
        for (int k = 0; k < 8; ++k) {
            float v = el[s_cur[k] * 8 + hh] + er_hh;
            v = (v >= 0.f) ? v : 0.2f * v;
            ex[k] = __expf(v);
            ss += ex[k];
        }
#pragma unroll
        for (int k = 0; k < 8; ++k) {
            unsigned short u[8];
            *(uint4*)u = r[k];
            for (int j = 0; j < 8; ++j) acc[j] += ex[k] * bfbits2f(u[j]);
        }
#pragma unroll
        for (int k = 0; k < 8; ++k) s_cur[k] = s_nxt[k];
    }
    // tail
    for (int i = nfull; i < deg; ++i) {
        int s = ecol[beg + i];
        uint4 r = *(const uint4*)(hp + (size_t)s * 256 + l * 8);
        float v = el[s * 8 + hh] + er_hh;
        v = (v >= 0.f) ? v : 0.2f * v;
        float e = __expf(v);
        ss += e;
        unsigned short u[8];
        *(uint4*)u = r;
        for (int j = 0; j < 8; ++j) acc[j] += e * bfbits2f(u[j]);
    }

    float inv = 1.f / (ss + 1e-16f);
    unsigned short o[8];
    for (int j = 0; j < 8; ++j) {
        float vv = acc[j] * inv;
        vv = (vv > 0.f) ? vv : expm1f(vv);   // ELU
        o[j] = f2bfbits(vv);
    }
    *(uint4*)((unsigned short*)out + (size_t)n * 256 + l * 8) = *(uint4*)o;
}

// ---------- output layer: 8-way vectorized aggregation (stride-64 Hp) + log_softmax ----------
__global__ __launch_bounds__(64)
void aggr_out_k(const int* __restrict__ rowptr, const int* __restrict__ ecol,
                const float* __restrict__ elo, const float* __restrict__ ero,
                const unsigned short* __restrict__ Hp64, void* __restrict__ outp,
                const int* __restrict__ flag, int N) {
    int n = blockIdx.x, l = threadIdx.x;
    int g = l >> 3, f = l & 7;
    int beg = rowptr[n], deg = rowptr[n + 1] - beg;
    float ero_n = ero[n];
    float ss = 0.f;
    float acc[8] = {0.f, 0.f, 0.f, 0.f, 0.f, 0.f, 0.f, 0.f};
    for (int i = g; i < deg; i += 8) {
        int s = ecol[beg + i];
        float v = elo[s] + ero_n;
        v = (v >= 0.f) ? v : 0.2f * v;
        float ex = __expf(v);
        ss += ex;
        uint4 r = *(const uint4*)(Hp64 + (size_t)s * 64 + f * 8);
        unsigned short u[8];
        *(uint4*)u = r;
        for (int j = 0; j < 8; ++j) acc[j] += ex * bfbits2f(u[j]);
    }
    for (int off = 8; off <= 32; off <<= 1) {
        ss += __shfl_xor(ss, off, 64);
        for (int j = 0; j < 8; ++j) acc[j] += __shfl_xor(acc[j], off, 64);
    }
    float inv = 1.f / (ss + 1e-16f);
    float r8[8];
    float vmax = -1e30f;
    for (int j = 0; j < 8; ++j) {
        r8[j] = acc[j] * inv;
        if (f < 5) vmax = fmaxf(vmax, r8[j]);
    }
    for (int off = 1; off <= 4; off <<= 1) vmax = fmaxf(vmax, __shfl_xor(vmax, off, 64));
    float es = 0.f;
    if (f < 5)
        for (int j = 0; j < 8; ++j) es += __expf(r8[j] - vmax);
    for (int off = 1; off <= 4; off <<= 1) es += __shfl_xor(es, off, 64);
    float lse = vmax + logf(es);
    if (f < 5 && g == 0) {
        if (*flag) {
            unsigned short o[8];
            for (int j = 0; j < 8; ++j) o[j] = f2bfbits(r8[j] - lse);
            *(uint4*)((unsigned short*)outp + (size_t)n * 40 + f * 8) = *(uint4*)o;
        } else {
            float* fo = (float*)outp + (size_t)n * 40 + f * 8;
            for (int j = 0; j < 8; ++j) fo[j] = r8[j] - lse;
        }
    }
}

extern "C" void kernel_launch(void* const* d_in, const int* in_sizes, int n_in,
                              void* d_out, int out_size, void* d_ws, size_t ws_size,
                              hipStream_t stream) {
    const int N = N_NODES, E = N_EDGES;
    const void* x   = d_in[0];
    const int* src  = (const int*)d_in[1];
    const int* dst  = (const int*)d_in[2];
    const void* W1  = d_in[3];
    const void* al1 = d_in[4];
    const void* ar1 = d_in[5];
    const void* W2  = d_in[6];
    const void* al2 = d_in[7];
    const void* ar2 = d_in[8];
    const void* Wo  = d_in[9];
    const void* alo = d_in[10];
    const void* aro = d_in[11];

    // workspace (~58.6 MB)
    char* w = (char*)d_ws;
    auto alloc = [&](size_t bytes) { void* p = (void*)w; w += (bytes + 255) & ~(size_t)255; return p; };
    int* flag      = (int*)alloc(4);
    int* rowptr    = (int*)alloc((size_t)(N + 1) * 4);
    int* cursor    = (int*)alloc((size_t)N * 4);
    float* elo     = (float*)alloc((size_t)N * 4);
    float* ero     = (float*)alloc((size_t)N * 4);
    int* bsum      = (int*)alloc(256 * 4);
    int* ecol      = (int*)alloc((size_t)E * 4);
    float* el      = (float*)alloc((size_t)N * 8 * 4);
    float* er      = (float*)alloc((size_t)N * 8 * 4);
    unsigned short* W1f = (unsigned short*)alloc((size_t)128 * 256 * 2);
    unsigned short* W2f = (unsigned short*)alloc((size_t)256 * 256 * 2);
    unsigned short* Wof = (unsigned short*)alloc((size_t)256 * 64 * 2);
    __hip_bfloat16* Hp   = (__hip_bfloat16*)alloc((size_t)N * 256 * 2);
    __hip_bfloat16* Hagg = (__hip_bfloat16*)alloc((size_t)N * 256 * 2);
    unsigned short* Xb = (unsigned short*)Hagg;   // alias: dead after layer-1 gemm

    int EB = (E + 255) / 256;
    int NB = (N + 255) / 256;
    int MB = (N + 127) / 128;
    int AB = (N + 7) / 8;

    cvt_all_k<<<(814336 + 255) / 256, 256, 0, stream>>>(x, W1, W2, Wo, Xb, W1f, W2f, Wof, flag);
    hipMemsetAsync(cursor, 0, (size_t)N * 3 * 4, stream);  // cursor + elo + ero
    hist_k<<<EB, 256, 0, stream>>>(dst, cursor, E);
    scan1_k<<<NB, 256, 0, stream>>>(cursor, rowptr, bsum, N);
    scan23_k<<<NB, 256, 0, stream>>>(rowptr, bsum, N, E);
    scatter_k<<<EB, 256, 0, stream>>>(src, dst, rowptr, cursor, ecol, E);

    // layer 1
    gemm_attn_k<128, 0><<<dim3(MB, 4), 256, 0, stream>>>(Xb, W1f, Hp, al1, ar1, flag, el, er, N, 256, 256);
    aggr1_k<<<AB, 256, 0, stream>>>(rowptr, ecol, el, er, Hp, Hagg, N);

    // layer 2
    gemm_attn_k<256, 0><<<dim3(MB, 4), 256, 0, stream>>>((const unsigned short*)Hagg, W2f, Hp, al2, ar2, flag, el, er, N, 256, 256);
    aggr1_k<<<AB, 256, 0, stream>>>(rowptr, ecol, el, er, Hp, Hagg, N);

    // output layer (C stored with stride 64, zero-padded cols 40..63)
    gemm_attn_k<256, 1><<<dim3(MB, 1), 256, 0, stream>>>((const unsigned short*)Hagg, Wof, Hp, alo, aro, flag, elo, ero, N, 40, 64);
    aggr_out_k<<<N, 64, 0, stream>>>(rowptr, ecol, elo, ero, (const unsigned short*)Hp, d_out, flag, N);
}